// Round 9
// baseline (944.457 us; speedup 1.0000x reference)
//
#include <hip/hip_runtime.h>
#include <hip/hip_bf16.h>

#define NH 256      // H
#define NE 768      // E
#define NH2 512
#define NG3 768     // 3*H
#define NB 16
#define NLF 32
#define NBT 2048    // 4 fields * 16 * 32 rows
#define NDE 2048

typedef short s16x8 __attribute__((ext_vector_type(8)));
typedef float f32x4 __attribute__((ext_vector_type(4)));

// swizzle: granule g (8 bf16) of row r stored at position (g + (r>>1)) & 3
#define TK_SWZ(g, r) (((g) + ((r) >> 1)) & 3)

#if __has_builtin(__builtin_amdgcn_global_load_lds)
#define GLOAD_LDS16(gp, lp) \
  __builtin_amdgcn_global_load_lds((const __attribute__((address_space(1))) unsigned int*)(gp), \
                                   (__attribute__((address_space(3))) unsigned int*)(lp), 16, 0, 0)
#define HAVE_GLLDS 1
#else
#define HAVE_GLLDS 0
#endif

// barrier that only drains LDS ops (NOT vmcnt) — keeps global loads/stores in flight.
// Safe here: cross-wave dependency at the barrier is LDS-only (h exchange).
__device__ __forceinline__ void barrier_lgkm_(){
  __asm__ volatile("s_waitcnt lgkmcnt(0)\n\ts_barrier" ::: "memory");
}

// fast transcendentals: v_exp_f32 + v_rcp_f32
__device__ __forceinline__ float fsig_(float x){
  return __builtin_amdgcn_rcpf(1.f + __expf(-x));
}
__device__ __forceinline__ float ftanh_(float x){
  float e = __expf(2.f*x);
  return 1.f - 2.f*__builtin_amdgcn_rcpf(e + 1.f);
}
__device__ __forceinline__ unsigned short f2bf_(float f){
  unsigned int x = __float_as_uint(f);
  unsigned int r = (x + 0x7fffu + ((x>>16)&1u)) >> 16;
  return (unsigned short)r;
}
__device__ __forceinline__ float bfx_(unsigned int u){ return __uint_as_float(u << 16); }
// pack 2 floats to 2 bf16 (round-half-up) in one u32: low=a, high=b
__device__ __forceinline__ unsigned int pack_bf16_rnd(float a, float b){
  unsigned int ua = __float_as_uint(a) + 0x8000u;
  unsigned int ub = __float_as_uint(b) + 0x8000u;
  return __builtin_amdgcn_perm(ub, ua, 0x07060302u);
}
// row in the (2048 x 512) embedding buffer for (side, b, tok)
__device__ __forceinline__ int tokrow(int side, int b, int tok){
  return (((side*2 + (tok>>5))*16 + b) << 5) + (tok & 31);
}
// extract bf16 element idx from a uint4[3] register block (compile-time idx)
__device__ __forceinline__ float xiget_(const uint4* x4, int idx){
  const unsigned int* w = (const unsigned int*)x4;
  unsigned int v = w[idx >> 1];
  return (idx & 1) ? __uint_as_float(v & 0xffff0000u) : __uint_as_float(v << 16);
}

// ---------------- gather 4 fields into X0 (2048 x 768) ----------------
__global__ void k_gather(const float* __restrict__ f0, const float* __restrict__ f1,
                         const float* __restrict__ f2, const float* __restrict__ f3,
                         float* __restrict__ X0){
  int m = blockIdx.x;
  int f = m >> 9, rem = m & 511;
  const float* src = (f==0)? f0 : (f==1)? f1 : (f==2)? f2 : f3;
  const float* sp = src + (size_t)rem*NE;
  float* dp = X0 + (size_t)m*NE;
  for (int d = threadIdx.x; d < NE; d += 256) dp[d] = sp[d];
}

// ---------------- token & attribute masks ----------------
__global__ void k_masks(const float* __restrict__ f0, const float* __restrict__ f1,
                        const float* __restrict__ f2, const float* __restrict__ f3,
                        float* __restrict__ TM, float* __restrict__ AM){
  int f = blockIdx.x, b = blockIdx.y;
  const float* src = (f==0)? f0 : (f==1)? f1 : (f==2)? f2 : f3;
  __shared__ unsigned int flags[33];
  if (threadIdx.x < 33) flags[threadIdx.x] = 0u;
  __syncthreads();
  for (int t = 0; t < 32; t++){
    const float* row = src + ((size_t)b*NLF + t)*NE;
    bool nz = false;
    for (int d = threadIdx.x; d < NE; d += 256) nz |= (row[d] != 0.f);
    if (nz) atomicOr(&flags[t], 1u);
  }
  __syncthreads();
  int side = f >> 1, fi = f & 1;
  if (threadIdx.x < 32){
    unsigned int fl = flags[threadIdx.x];
    TM[side*1024 + b*64 + fi*32 + threadIdx.x] = fl ? 1.f : 0.f;
    if (fl) atomicOr(&flags[32], 1u);
  }
  __syncthreads();
  if (threadIdx.x == 0) AM[side*32 + b*2 + fi] = flags[32] ? 1.f : 0.f;
}

// ---------------- convert all 6 Whh chains to bf16 ----------------
__global__ void k_prep_whh(const float* __restrict__ w0, const float* __restrict__ w12,
                           unsigned short* __restrict__ dst){
  int idx = blockIdx.x*256 + threadIdx.x;   // < 1179648
  float v = (idx < 393216) ? w0[idx] : w12[idx - 393216];
  dst[idx] = f2bf_(v);
}

// ---------------- prep token weights: TW[nc][kc][n(interleaved)][k32] bf16, pre-swizzled ----------------
__global__ void k_prep_tw(const float* __restrict__ Wn, const float* __restrict__ Wg,
                          unsigned short* __restrict__ TW){
  int idx = blockIdx.x*256 + threadIdx.x;   // < 524288
  int kpos = idx & 31;
  int n    = (idx >> 5) & 127;
  int kc   = (idx >> 12) & 15;
  int nc   = idx >> 16;
  int gpos = kpos >> 3, j = kpos & 7;
  int gorig = (gpos - (n>>1)) & 3;
  int k = kc*32 + gorig*8 + j;
  int q = n >> 1, type = n & 1;
  const float* src = type ? Wg : Wn;
  TW[idx] = f2bf_(src[(size_t)(nc*64 + q)*NH2 + k]);
}

// ---------------- bf16 MFMA NT GEMM -> XI[dir][t][g][tid][24] bf16 (scan-thread order) ----------------
template<bool ABF16>
__global__ __launch_bounds__(256) void k_gemm_mfma(
    const void* __restrict__ Av,
    const float* __restrict__ Wb, long wsz,
    const float* __restrict__ biasb, long bsz,
    unsigned short* __restrict__ XIo, long csz,
    int K)
{
  int z = blockIdx.z;
  const float* W = Wb + (size_t)z*wsz;
  const float* bias = biasb + (size_t)z*bsz;
  unsigned short* XO = XIo + (size_t)z*csz;
  int n0 = blockIdx.x*128, m0 = blockIdx.y*128;
  __shared__ short At[128*32];
  __shared__ short Wt[128*32];
  int tid = threadIdx.x;
  int wave = tid >> 6, wm = wave >> 1, wn = wave & 1;
  int lane = tid & 63, l15 = lane & 15, lq = lane >> 4;
  int sm = tid & 127, gb = (tid >> 7) * 2;

  f32x4 zero4 = {0.f,0.f,0.f,0.f};
  f32x4 acc[4][4];
  #pragma unroll
  for (int mi=0;mi<4;mi++)
    #pragma unroll
    for (int nj=0;nj<4;nj++) acc[mi][nj] = zero4;

  const float* wr = W + (size_t)(n0 + sm)*K;

  for (int k0 = 0; k0 < K; k0 += 32){
    if constexpr (ABF16){
      const unsigned short* ar = (const unsigned short*)Av + (size_t)(m0 + sm)*K;
      #pragma unroll
      for (int gi = 0; gi < 2; gi++){
        int g = gb + gi;
        *(uint4*)&At[sm*32 + TK_SWZ(g,sm)*8] = *(const uint4*)&ar[k0 + g*8];
      }
    } else {
      const float* ar = (const float*)Av + (size_t)(m0 + sm)*K;
      #pragma unroll
      for (int gi = 0; gi < 2; gi++){
        int g = gb + gi;
        const float* ap = ar + k0 + g*8;
        float4 a0 = *(const float4*)ap, a1 = *(const float4*)(ap+4);
        uint4 pa = { pack_bf16_rnd(a0.x,a0.y), pack_bf16_rnd(a0.z,a0.w),
                     pack_bf16_rnd(a1.x,a1.y), pack_bf16_rnd(a1.z,a1.w) };
        *(uint4*)&At[sm*32 + TK_SWZ(g,sm)*8] = pa;
      }
    }
    #pragma unroll
    for (int gi = 0; gi < 2; gi++){
      int g = gb + gi;
      const float* wp = wr + k0 + g*8;
      float4 w0 = *(const float4*)wp, w1 = *(const float4*)(wp+4);
      uint4 pw = { pack_bf16_rnd(w0.x,w0.y), pack_bf16_rnd(w0.z,w0.w),
                   pack_bf16_rnd(w1.x,w1.y), pack_bf16_rnd(w1.z,w1.w) };
      *(uint4*)&Wt[sm*32 + TK_SWZ(g,sm)*8] = pw;
    }
    __syncthreads();
    s16x8 af[4], wf[4];
    #pragma unroll
    for (int mi=0;mi<4;mi++){
      int row = wm*64 + mi*16 + l15;
      af[mi] = *(const s16x8*)&At[row*32 + TK_SWZ(lq,row)*8];
    }
    #pragma unroll
    for (int nj=0;nj<4;nj++){
      int row = wn*64 + nj*16 + l15;
      wf[nj] = *(const s16x8*)&Wt[row*32 + TK_SWZ(lq,row)*8];
    }
    #pragma unroll
    for (int mi=0;mi<4;mi++)
      #pragma unroll
      for (int nj=0;nj<4;nj++)
        acc[mi][nj] = __builtin_amdgcn_mfma_f32_16x16x32_bf16(af[mi], wf[nj], acc[mi][nj], 0,0,0);
    __syncthreads();
  }
  // epilogue: write into scan-thread layout XI[t][g][tid_s][24]
  #pragma unroll
  for (int nj=0;nj<4;nj++){
    int n = n0 + wn*64 + nj*16 + l15;
    float bv = bias[n];
    int gg = n >> 8;
    int u256 = n & 255;
    int p = u256 >> 7, w_s = (u256 >> 4) & 7, l15_s = u256 & 15;
    int cofs = (p*3 + gg)*4;
    #pragma unroll
    for (int mi=0;mi<4;mi++){
      int mbase = m0 + wm*64 + mi*16 + lq*4;
      int t0 = mbase & 31, bp = mbase >> 5;
      int g = bp >> 4, mloc = bp & 15;
      int lq_s = mloc >> 2, r4 = mloc & 3;
      int tid_s = w_s*64 + lq_s*16 + l15_s;
      size_t base = ((size_t)(t0*4 + g)*512 + tid_s)*24 + cofs + r4;
      #pragma unroll
      for (int r=0;r<4;r++)
        XO[base + (size_t)r*49152] = f2bf_(acc[mi][nj][r] + bv);
    }
  }
}

// ---------------- GRU scan step body ----------------
__device__ __forceinline__ void scan_step_(
    const unsigned short* __restrict__ rbp, unsigned short* __restrict__ wbp,
    const uint4* xv, int t, int b0, int w, int l15, int lq, int dir,
    const s16x8 (&warr)[6][8], const float* brv, const float* bzv, const float* bnv,
    float (&hreg)[2][4], unsigned short* __restrict__ Hout)
{
  f32x4 acc[6];
  #pragma unroll
  for (int p6 = 0; p6 < 6; p6++) acc[p6] = (f32x4){0.f,0.f,0.f,0.f};
  #pragma unroll
  for (int kt = 0; kt < 8; kt++){
    s16x8 a = *(const s16x8*)&rbp[l15*264 + kt*32 + lq*8];
    #pragma unroll
    for (int p6 = 0; p6 < 6; p6++)
      acc[p6] = __builtin_amdgcn_mfma_f32_16x16x32_bf16(a, warr[p6][kt], acc[p6], 0,0,0);
  }
  #pragma unroll
  for (int p = 0; p < 2; p++){
    int u = p*128 + 16*w + l15;
    #pragma unroll
    for (int r4 = 0; r4 < 4; r4++){
      int m = lq*4 + r4;
      float xr_ = xiget_(xv, (p*3+0)*4 + r4);
      float xz_ = xiget_(xv, (p*3+1)*4 + r4);
      float xn_ = xiget_(xv, (p*3+2)*4 + r4);
      float rr = fsig_(xr_ + acc[p][r4]   + brv[p]);
      float zz = fsig_(xz_ + acc[2+p][r4] + bzv[p]);
      float nn = ftanh_(xn_ + rr*(acc[4+p][r4] + bnv[p]));
      float hnew = (1.f - zz)*nn + zz*hreg[p][r4];
      hreg[p][r4] = hnew;
      unsigned short hb = f2bf_(hnew);
      wbp[m*264 + u] = hb;
      Hout[((size_t)(b0 + m)*32 + t)*NH2 + dir*256 + u] = hb;
    }
  }
}

// ---------------- GRU scan via MFMA; weights register-resident; lgkm-only barrier ----------------
__global__ __launch_bounds__(512, 2) void k_scan_mfma(
    const unsigned short* __restrict__ xi,   // [2][32][4][512][24] bf16 (scan-thread order)
    const unsigned short* __restrict__ whh,  // [6][768][256] bf16
    const float* __restrict__ bhhb, long bhh_stride,
    unsigned short* __restrict__ Hout,       // [2048][512] bf16
    int chain0)
{
  int g = blockIdx.x;        // b' in [16g, 16g+16)
  int dir = blockIdx.y;
  int tid = threadIdx.x;
  int w = tid >> 6;
  int lane = tid & 63, l15 = lane & 15, lq = lane >> 4;
  const unsigned short* W = whh + (size_t)(chain0 + dir)*NG3*NH;
  const float* bhh = bhhb + (size_t)dir*bhh_stride;
  const unsigned short* xid = xi + (size_t)dir*1572864;
  int b0 = g*16;

  __shared__ unsigned short hbuf[2*16*264];
  for (int i = tid; i < 2*16*264; i += 512) hbuf[i] = 0;

  uint4 xA[3], xB[3];
  {
    int t0 = dir ? 31 : 0;
    const uint4* p0 = (const uint4*)(xid + ((size_t)(t0*4 + g)*512 + tid)*24);
    xA[0] = p0[0]; xA[1] = p0[1]; xA[2] = p0[2];
  }

  s16x8 warr[6][8];
  #pragma unroll
  for (int p6 = 0; p6 < 6; p6++){
    const unsigned short* wp = W + (size_t)(16*(w + 8*p6) + l15)*NH + lq*8;
    #pragma unroll
    for (int kt = 0; kt < 8; kt++)
      warr[p6][kt] = *(const s16x8*)(wp + kt*32);
  }
  float brv[2], bzv[2], bnv[2];
  #pragma unroll
  for (int p = 0; p < 2; p++){
    int u = p*128 + 16*w + l15;
    brv[p] = bhh[u]; bzv[p] = bhh[256+u]; bnv[p] = bhh[512+u];
  }
  float hreg[2][4] = {{0,0,0,0},{0,0,0,0}};
  __syncthreads();

  #pragma unroll 1
  for (int sp = 0; sp < 16; sp++){
    int s0 = sp*2;
    // ---- even step: read hbuf[0], write hbuf[1], use xA; prefetch xB for s0+1
    {
      int t  = dir ? (31 - s0) : s0;
      int tn = dir ? (31 - (s0+1)) : (s0+1);
      const uint4* pn = (const uint4*)(xid + ((size_t)(tn*4 + g)*512 + tid)*24);
      xB[0] = pn[0]; xB[1] = pn[1]; xB[2] = pn[2];
      scan_step_(hbuf, hbuf + 4224, xA, t, b0, w, l15, lq, dir,
                 warr, brv, bzv, bnv, hreg, Hout);
      barrier_lgkm_();
    }
    // ---- odd step: read hbuf[1], write hbuf[0], use xB; prefetch xA for s0+2
    {
      int s1 = s0 + 1;
      int t = dir ? (31 - s1) : s1;
      if (s1 < 31){
        int tn = dir ? (31 - (s1+1)) : (s1+1);
        const uint4* pn = (const uint4*)(xid + ((size_t)(tn*4 + g)*512 + tid)*24);
        xA[0] = pn[0]; xA[1] = pn[1]; xA[2] = pn[2];
      }
      scan_step_(hbuf + 4224, hbuf, xB, t, b0, w, l15, lq, dir,
                 warr, brv, bzv, bnv, hreg, Hout);
      barrier_lgkm_();
    }
  }
}

// ---------------- precompute cm tiles from bf16 H ----------------
__global__ __launch_bounds__(256) void k_cm_pretile(
    const unsigned short* __restrict__ Hf, unsigned short* __restrict__ CMT, int b0)
{
  int ip = blockIdx.x, bl = blockIdx.y;
  int b = b0 + bl;
  int tid = threadIdx.x;
  int m = tid & 127, gb = (tid >> 7) * 2;
  int i_ = ip*2 + (m >> 6), j_ = m & 63;
  const unsigned short* Lrow = Hf + (size_t)tokrow(0, b, i_)*NH2;
  const unsigned short* Rrow = Hf + (size_t)tokrow(1, b, j_)*NH2;
  unsigned short* dst = CMT + ((size_t)(bl*32 + ip) * 16) * 4096;
  for (int kc = 0; kc < 16; kc++){
    int k0 = kc*32;
    #pragma unroll
    for (int gi = 0; gi < 2; gi++){
      int g = gb + gi;
      uint4 lu = *(const uint4*)&Lrow[k0 + g*8];
      uint4 ru = *(const uint4*)&Rrow[k0 + g*8];
      unsigned int lw[4] = {lu.x, lu.y, lu.z, lu.w};
      unsigned int rw[4] = {ru.x, ru.y, ru.z, ru.w};
      uint4 pk;
      unsigned int pr[4];
      #pragma unroll
      for (int q = 0; q < 4; q++){
        float la = __uint_as_float(lw[q] << 16), lb = __uint_as_float(lw[q] & 0xffff0000u);
        float ra = __uint_as_float(rw[q] << 16), rb = __uint_as_float(rw[q] & 0xffff0000u);
        pr[q] = pack_bf16_rnd(fabsf(la - ra), fabsf(lb - rb));
      }
      pk.x = pr[0]; pk.y = pr[1]; pk.z = pr[2]; pk.w = pr[3];
      *(uint4*)&dst[kc*4096 + m*32 + TK_SWZ(g,m)*8] = pk;
    }
  }
}

// ---------------- token-matching scores via MFMA (DMA-staged tiles) ----------------
__global__ __launch_bounds__(256) void k_token_mfma(
    const unsigned short* __restrict__ CMT,
    const unsigned short* __restrict__ TW,
    const float* __restrict__ bn, const float* __restrict__ bg,
    const float* __restrict__ lintW,
    float* __restrict__ P, int b0)
{
  __shared__ short Atile[4096];
  __shared__ short Btile[4096];
  __shared__ short Asave[8192];
  __shared__ float sred[256];
  int ip = blockIdx.x, bl = blockIdx.y, nc = blockIdx.z;
  int b = b0 + bl;
  int tid = threadIdx.x;
  int wave = tid >> 6, wm = wave >> 1, wn = wave & 1;
  int lane = tid & 63, l15 = lane & 15, lq = lane >> 4;

  const char* Ab = (const char*)(CMT + ((size_t)(bl*32 + ip) * 16) * 4096);
  const char* Bb = (const char*)(TW + ((size_t)(nc*16)) * 4096);

  f32x4 zero4 = {0.f,0.f,0.f,0.f};
  f32x4 acc[4][4];
  #pragma unroll
  for (int mi=0;mi<4;mi++)
    #pragma unroll
    for (int nj=0;nj<4;nj++) acc[mi][nj] = zero4;

  for (int kc = 0; kc < 16; kc++){
    const char* gA = Ab + (size_t)kc*8192;
    const char* gB = Bb + (size_t)kc*8192;
#if HAVE_GLLDS
    char* lA = (char*)Atile + wave*1024;
    char* lB = (char*)Btile + wave*1024;
    GLOAD_LDS16(gA + tid*16, lA);
    GLOAD_LDS16(gA + 4096 + tid*16, lA + 4096);
    GLOAD_LDS16(gB + tid*16, lB);
    GLOAD_LDS16(gB + 4096 + tid*16, lB + 4096);
    int cs = kc - 2*nc;
    if ((unsigned)cs < 2u){
      char* lS = (char*)Asave + cs*8192 + wave*1024;
      GLOAD_LDS16(gA + tid*16, lS);
      GLOAD_LDS16(gA + 4096 + tid*16, lS + 4096);
    }
#else
    {
      uint4 va0 = ((const uint4*)gA)[tid], va1 = ((const uint4*)gA)[256+tid];
      uint4 vb0 = ((const uint4*)gB)[tid], vb1 = ((const uint4*)gB)[256+tid];
      ((uint4*)Atile)[tid] = va0; ((uint4*)Atile)[256+tid] = va1;
      ((uint4*)Btile)[tid] = vb0; ((uint4*)Btile)[256+tid] = vb1;
      int cs = kc - 2*nc;
      if ((unsigned)cs < 2u){
        ((uint4*)Asave)[cs*512 + tid] = va0; ((uint4*)Asave)[cs*512 + 256+tid] = va1;
      }
    }
#endif
    __syncthreads();
    s16x8 af[4], bfv[4];
    #pragma unroll
    for (int mi=0;mi<4;mi++){
      int row = wm*64 + mi*16 + l15;
      af[mi] = *(const s16x8*)&Atile[row*32 + TK_SWZ(lq,row)*8];
    }
    #pragma unroll
    for (int nj=0;nj<4;nj++){
      int row = wn*64 + nj*16 + l15;
      bfv[nj] = *(const s16x8*)&Btile[row*32 + TK_SWZ(lq,row)*8];
    }
    #pragma unroll
    for (int mi=0;mi<4;mi++)
      #pragma unroll
      for (int nj=0;nj<4;nj++)
        acc[mi][nj] = __builtin_amdgcn_mfma_f32_16x16x32_bf16(af[mi], bfv[nj], acc[mi][nj], 0,0,0);
    __syncthreads();
  }

  float bnv[4], bgv[4], lwv[4]; int qv[4];
  #pragma unroll
  for (int nj=0;nj<4;nj++){
    int q = (wn*64 + nj*16 + l15) >> 1;
    qv[nj] = q;
    int nf = nc*64 + q;
    bnv[nj] = bn[nf]; bgv[nj] = bg[nf]; lwv[nj] = lintW[nf];
  }
  float lmask = (l15 & 1) ? 0.f : 1.f;
  float sc[4][4];
  #pragma unroll
  for (int mi=0;mi<4;mi++)
    #pragma unroll
    for (int r=0;r<4;r++) sc[mi][r] = 0.f;

  #pragma unroll
  for (int nj=0;nj<4;nj++){
    int q = qv[nj];
    int cs = q >> 5, kk = q & 31, gor = kk >> 3, el = kk & 7;
    #pragma unroll
    for (int mi=0;mi<4;mi++){
      int mbase = wm*64 + mi*16 + lq*4;
      #pragma unroll
      for (int r=0;r<4;r++){
        float v  = acc[mi][nj][r];
        float pv = __shfl_xor(v, 1);
        int mm = mbase + r;
        unsigned short cu = (unsigned short)Asave[cs*4096 + mm*32 + TK_SWZ(gor,mm)*8 + el];
        float cmf = __uint_as_float(((unsigned int)cu) << 16);
        float an = v + bnv[nj];
        float gg = fsig_(pv + bgv[nj]);
        float hw = fmaxf(an, 0.f)*gg + (1.f - gg)*cmf;
        sc[mi][r] += lmask * lwv[nj] * hw;
      }
    }
  }
  #pragma unroll
  for (int mi=0;mi<4;mi++)
    #pragma unroll
    for (int r=0;r<4;r++){
      float v = sc[mi][r];
      v += __shfl_xor(v, 1); v += __shfl_xor(v, 2);
      v += __shfl_xor(v, 4); v += __shfl_xor(v, 8);
      sc[mi][r] = v;
    }
  if (l15 == 0){
    #pragma unroll
    for (int mi=0;mi<4;mi++)
      #pragma unroll
      for (int r=0;r<4;r++)
        sred[(wm*64 + mi*16 + lq*4 + r)*2 + wn] = sc[mi][r];
  }
  __syncthreads();
  if (tid < 128){
    float v = sred[tid*2] + sred[tid*2+1];
    int isel = tid >> 6, j = tid & 63;
    P[(((size_t)nc*16 + b)*64 + (ip*2 + isel))*64 + j] = v;
  }
}

__global__ void k_score_reduce(const float* __restrict__ P, float* __restrict__ S){
  int idx = blockIdx.x*256 + threadIdx.x;  // 65536
  float v = 0.f;
  #pragma unroll
  for (int nc = 0; nc < 8; nc++) v += P[(size_t)nc*65536 + idx];
  S[idx] = v;
}

// ---------------- softmaxes over j (w_l) and over i (w_r) ----------------
__global__ void k_softmax_wl(const float* __restrict__ S, const float* __restrict__ TM,
                             float* __restrict__ WLo){
  int i = blockIdx.x, b = blockIdx.y, j = threadIdx.x;
  float mask = TM[1024 + b*64 + j];
  float v = S[((size_t)b*64 + i)*64 + j] + (mask != 0.f ? 0.f : -1e10f);
  float m = v;
  for (int o = 32; o; o >>= 1) m = fmaxf(m, __shfl_xor(m, o));
  float e = __expf(v - m), s = e;
  for (int o = 32; o; o >>= 1) s += __shfl_xor(s, o);
  WLo[((size_t)b*64 + i)*64 + j] = e / s;
}
__global__ void k_softmax_wr(const float* __restrict__ S, const float* __restrict__ TM,
                             float* __restrict__ WRo){
  int j = blockIdx.x, b = blockIdx.y, i = threadIdx.x;
  float mask = TM[b*64 + i];
  float v = S[((size_t)b*64 + i)*64 + j] + (mask != 0.f ? 0.f : -1e10f);
  float m = v;
  for (int o = 32; o; o >>= 1) m = fmaxf(m, __shfl_xor(m, o));
  float e = __expf(v - m), s = e;
  for (int o = 32; o; o >>= 1) s += __shfl_xor(s, o);
  WRo[((size_t)b*64 + j)*64 + i] = e / s;
}

// ---------------- weighted |L-R| sums (bf16 H) ----------------
__global__ __launch_bounds__(256) void k_cmp(const unsigned short* __restrict__ Hf,
    const float* __restrict__ w, float* __restrict__ out, int side){
  int p = blockIdx.x, b = blockIdx.y;
  __shared__ float wl[64];
  if (threadIdx.x < 64) wl[threadIdx.x] = w[((size_t)b*64 + p)*64 + threadIdx.x];
  __syncthreads();
  int xr = tokrow(side, b, p);
  int d1 = threadIdx.x, d2 = threadIdx.x + 256;
  float x1 = bfx_(Hf[(size_t)xr*NH2 + d1]), x2 = bfx_(Hf[(size_t)xr*NH2 + d2]);
  float a1 = 0.f, a2 = 0.f;
  for (int q = 0; q < 64; q++){
    const unsigned short* yr = Hf + (size_t)tokrow(side^1, b, q)*NH2;
    float wq = wl[q];
    a1 += wq * fabsf(x1 - bfx_(yr[d1]));
    a2 += wq * fabsf(x2 - bfx_(yr[d2]));
  }
  out[((size_t)b*64 + p)*NH2 + d1] = a1;
  out[((size_t)b*64 + p)*NH2 + d2] = a2;
}

// ---------------- attribute matching -> concat buffer ----------------
__global__ __launch_bounds__(256) void k_attr(const unsigned short* __restrict__ Hf,
    const float* __restrict__ attrL, const float* __restrict__ attrR,
    const float* __restrict__ LC, const float* __restrict__ RC,
    const float* __restrict__ TM, const float* __restrict__ AM,
    const float* __restrict__ emptyA, float* __restrict__ CC){
  int fi = blockIdx.x, b = blockIdx.y, side = blockIdx.z;
  const float* attr = (side ? attrR : attrL) + fi*512;
  const float* cmp = side ? RC : LC;
  __shared__ float sc[32], wv[32];
  int t = threadIdx.x >> 3, l8 = threadIdx.x & 7;
  const unsigned short* er = Hf + (size_t)tokrow(side, b, fi*32 + t)*NH2;
  float acc = 0.f;
  for (int d = l8*64; d < l8*64 + 64; d++) acc += bfx_(er[d])*attr[d];
  acc += __shfl_down(acc, 4, 8);
  acc += __shfl_down(acc, 2, 8);
  acc += __shfl_down(acc, 1, 8);
  if (l8 == 0) sc[t] = acc;
  __syncthreads();
  if (threadIdx.x < 32){
    float mask = TM[side*1024 + b*64 + fi*32 + threadIdx.x];
    float v = sc[threadIdx.x] + (mask != 0.f ? 0.f : -1e10f);
    float m = v;
    for (int o = 16; o; o >>= 1) m = fmaxf(m, __shfl_xor(m, o, 32));
    float e = __expf(v - m), s = e;
    for (int o = 16; o; o >>= 1) s += __shfl_xor(s, o, 32);
    wv[threadIdx.x] = e / s;
  }
  __syncthreads();
  float am = AM[side*32 + b*2 + fi];
  int d1 = threadIdx.x, d2 = threadIdx.x + 256;
  float a1 = 0.f, a2 = 0.f;
  for (int t2 = 0; t2 < 32; t2++){
    float wq = wv[t2];
    const float* cr = cmp + ((size_t)b*64 + fi*32 + t2)*NH2;
    a1 += wq * cr[d1];
    a2 += wq * cr[d2];
  }
  float* dst = CC + (size_t)b*NDE + (size_t)(side*2 + fi)*512;
  dst[d1] = (am != 0.f) ? a1 : emptyA[d1];
  dst[d2] = (am != 0.f) ? a2 : emptyA[d2];
}

// ---------------- final highway: K-split MFMA GEMM -> partials ----------------
__global__ __launch_bounds__(256) void k_final_gemm(
    const float* __restrict__ X,     // CC [16][2048]
    const float* __restrict__ Wn, const float* __restrict__ Wg,
    float* __restrict__ P2)          // [2][4][16][2048]
{
  int nt = blockIdx.x, ks = blockIdx.y, z = blockIdx.z;
  const float* W = z ? Wg : Wn;
  int n0 = nt*64, k0 = ks*512;
  __shared__ short At[16*32];
  __shared__ short Wt[64*32];
  int tid = threadIdx.x;
  int w = tid >> 6, lane = tid & 63, l15 = lane & 15, lq = lane >> 4;
  int sm = tid & 63, gW = tid >> 6;
  int sa = tid & 15, ga = (tid >> 4) & 3;

  f32x4 acc = {0.f,0.f,0.f,0.f};
  for (int kc = 0; kc < 16; kc++){
    int kk = k0 + kc*32;
    {
      const float* wp = W + (size_t)(n0 + sm)*NDE + kk + gW*8;
      float4 w0 = *(const float4*)wp, w1 = *(const float4*)(wp+4);
      uint4 pw = { pack_bf16_rnd(w0.x,w0.y), pack_bf16_rnd(w0.z,w0.w),
                   pack_bf16_rnd(w1.x,w1.y), pack_bf16_rnd(w1.z,w1.w) };
      *(uint4*)&Wt[sm*32 + TK_SWZ(gW,sm)*8] = pw;
    }
    if (tid < 64){
      const float* xp = X + (size_t)sa*NDE + kk + ga*8;
      float4 x0 = *(const float4*)xp, x1 = *(const float4*)(xp+4);
      uint4 pa = { pack_bf16_rnd(x0.x,x0.y), pack_bf16_rnd(x0.z,x0.w),
                   pack_bf16_rnd(x1.x,x1.y), pack_bf16_rnd(x1.z,x1.w) };
      *(uint4*)&At[sa*32 + TK_SWZ(ga,sa)*8] = pa;
    }
    __syncthreads();
    s16x8 af = *(const s16x8*)&At[l15*32 + TK_SWZ(lq,l15)*8];
    int row = w*16 + l15;
    s16x8 bf = *(const s16x8*)&Wt[row*32 + TK_SWZ(lq,row)*8];
    acc = __builtin_amdgcn_mfma_f32_16x16x32_bf16(af, bf, acc, 0,0,0);
    __syncthreads();
  }
  int n = n0 + w*16 + l15;
  #pragma unroll
  for (int r = 0; r < 4; r++){
    int b = lq*4 + r;
    P2[(((size_t)z*4 + ks)*16 + b)*NDE + n] = acc[r];
  }
}

__global__ void k_final_reduce(const float* __restrict__ P2,
    const float* __restrict__ X, const float* __restrict__ bn, const float* __restrict__ bg,
    float* __restrict__ HWo){
  int idx = blockIdx.x*256 + threadIdx.x;   // 32768
  int b = idx >> 11, n = idx & 2047;
  float an = bn[n], ag = bg[n];
  #pragma unroll
  for (int ks = 0; ks < 4; ks++){
    an += P2[((size_t)(0*4 + ks)*16 + b)*NDE + n];
    ag += P2[((size_t)(1*4 + ks)*16 + b)*NDE + n];
  }
  float g = fsig_(ag);
  float x = X[(size_t)b*NDE + n];
  HWo[(size_t)b*NDE + n] = fmaxf(an, 0.f)*g + (1.f - g)*x;
}

// ---------------- linear + log_softmax ----------------
__global__ void k_out(const float* __restrict__ HWi, const float* __restrict__ lw,
                      const float* __restrict__ lb, float* __restrict__ out){
  int b = blockIdx.x, lane = threadIdx.x;
  float p0 = 0.f, p1 = 0.f;
  for (int n = lane; n < 2048; n += 64){
    float h = HWi[(size_t)b*NDE + n];
    p0 += h * lw[n];
    p1 += h * lw[2048 + n];
  }
  for (int o = 32; o; o >>= 1){ p0 += __shfl_xor(p0, o); p1 += __shfl_xor(p1, o); }
  if (lane == 0){
    float o0 = p0 + lb[0], o1 = p1 + lb[1];
    float m = fmaxf(o0, o1);
    float lse = m + logf(expf(o0 - m) + expf(o1 - m));
    out[b*2]   = o0 - lse;
    out[b*2+1] = o1 - lse;
  }
}

extern "C" void kernel_launch(void* const* d_in, const int* in_sizes, int n_in,
                              void* d_out, int out_size, void* d_ws, size_t ws_size,
                              hipStream_t stream){
  const float* lf0 = (const float*)d_in[0];
  const float* lf1 = (const float*)d_in[1];
  const float* rf0 = (const float*)d_in[2];
  const float* rf1 = (const float*)d_in[3];
  const float* gWih0 = (const float*)d_in[4];
  const float* gWhh0 = (const float*)d_in[5];
  const float* gbih0 = (const float*)d_in[6];
  const float* gbhh0 = (const float*)d_in[7];
  const float* gWih12 = (const float*)d_in[8];
  const float* gWhh12 = (const float*)d_in[9];
  const float* gbih12 = (const float*)d_in[10];
  const float* gbhh12 = (const float*)d_in[11];
  const float* hwtWn = (const float*)d_in[12];
  const float* hwtbn = (const float*)d_in[13];
  const float* hwtWg = (const float*)d_in[14];
  const float* hwtbg = (const float*)d_in[15];
  const float* lintW = (const float*)d_in[16];
  // d_in[17] = lintB (dropped: softmax is shift-invariant)
  const float* attrL = (const float*)d_in[18];
  const float* attrR = (const float*)d_in[19];
  const float* emptyA = (const float*)d_in[20];
  const float* hweWn = (const float*)d_in[21];
  const float* hwebn = (const float*)d_in[22];
  const float* hweWg = (const float*)d_in[23];
  const float* hwebg = (const float*)d_in[24];
  const float* lineW = (const float*)d_in[25];
  const float* lineB = (const float*)d_in[26];
  float* out = (float*)d_out;

  // ws layout (~29 MB): persistent first; CMT region (16 MB) aliases X0+XI and P2
  unsigned short* HA = (unsigned short*)d_ws;              // 1048576 sh (2 MB)
  unsigned short* HB = HA + 1048576;                       // 1048576 sh
  unsigned short* WHH = HB + 1048576;                      // 1179648 sh
  unsigned short* TW  = WHH + 1179648;                     // 524288 sh
  float* Sb  = (float*)(TW + 524288);                      // 65536
  float* WLb = Sb  + 65536;
  float* WRb = WLb + 65536;
  float* LC  = WRb + 65536;                                // 524288
  float* RC  = LC + 524288;                                // 524288
  float* TM  = RC + 524288;                                // 2048
  float* AM  = TM + 2048;                                  // 64
  float* CC  = AM + 64;                                    // 32768
  float* HWb = CC + 32768;                                 // 32768
  float* P   = HWb + 32768;                                // 524288
  unsigned short* CMT = (unsigned short*)(P + 524288);     // 8388608 sh (16 MB)
  float* X0 = (float*)CMT;                                 // aliases CMT (dead after gemms)
  unsigned short* XI = (unsigned short*)(X0 + 1572864);    // aliases CMT
  float* P2 = (float*)CMT;                                 // 262144 f (1 MB), after token loop

  k_gather<<<NBT, 256, 0, stream>>>(lf0, lf1, rf0, rf1, X0);
  k_masks<<<dim3(4,16), 256, 0, stream>>>(lf0, lf1, rf0, rf1, TM, AM);
  k_prep_whh<<<4608, 256, 0, stream>>>(gWhh0, gWhh12, WHH);
  k_prep_tw<<<2048, 256, 0, stream>>>(hwtWn, hwtWg, TW);

  const long XSZ = 1572864;   // per-dir XI shorts
  // layer 0 (A fp32)
  k_gemm_mfma<false><<<dim3(6,16,2), 256, 0, stream>>>(X0, gWih0, (long)NG3*NE, gbih0, NG3,
                                                       XI, XSZ, NE);
  k_scan_mfma<<<dim3(4,2), 512, 0, stream>>>(XI, WHH, gbhh0, NG3, HA, 0);
  // layer 1 (A bf16)
  k_gemm_mfma<true><<<dim3(6,16,2), 256, 0, stream>>>(HA, gWih12, (long)NG3*NH2, gbih12, NG3,
                                                      XI, XSZ, NH2);
  k_scan_mfma<<<dim3(4,2), 512, 0, stream>>>(XI, WHH, gbhh12, NG3, HB, 2);
  // layer 2 (A bf16)
  k_gemm_mfma<true><<<dim3(6,16,2), 256, 0, stream>>>(HB, gWih12 + (size_t)2*NG3*NH2, (long)NG3*NH2,
                                                      gbih12 + 2*NG3, NG3,
                                                      XI, XSZ, NH2);
  k_scan_mfma<<<dim3(4,2), 512, 0, stream>>>(XI, WHH, gbhh12 + 2*NG3, NG3, HA, 4);

  // token matching: 4 b-chunks of 4 (CMT reused per chunk; XI dead by now)
  for (int c = 0; c < 4; c++){
    k_cm_pretile<<<dim3(32,4), 256, 0, stream>>>(HA, CMT, c*4);
    k_token_mfma<<<dim3(32,4,8), 256, 0, stream>>>(CMT, TW, hwtbn, hwtbg, lintW, P, c*4);
  }
  k_score_reduce<<<256, 256, 0, stream>>>(P, Sb);
  k_softmax_wl<<<dim3(64,16), 64, 0, stream>>>(Sb, TM, WLb);
  k_softmax_wr<<<dim3(64,16), 64, 0, stream>>>(Sb, TM, WRb);
  k_cmp<<<dim3(64,16), 256, 0, stream>>>(HA, WLb, LC, 0);
  k_cmp<<<dim3(64,16), 256, 0, stream>>>(HA, WRb, RC, 1);

  // attribute matching -> concat
  k_attr<<<dim3(2,16,2), 256, 0, stream>>>(HA, attrL, attrR, LC, RC, TM, AM, emptyA, CC);

  // final highway (K-split MFMA) + classifier
  k_final_gemm<<<dim3(32,4,2), 256, 0, stream>>>(CC, hweWn, hweWg, P2);
  k_final_reduce<<<128, 256, 0, stream>>>(P2, CC, hwebn, hwebg, HWb);
  k_out<<<16, 64, 0, stream>>>(HWb, lineW, lineB, out);
}

// Round 10
// 730.505 us; speedup vs baseline: 1.2929x; 1.2929x over previous
//
#include <hip/hip_runtime.h>
#include <hip/hip_bf16.h>

#define NH 256      // H
#define NE 768      // E
#define NH2 512
#define NG3 768     // 3*H
#define NB 16
#define NLF 32
#define NBT 2048    // 4 fields * 16 * 32 rows
#define NDE 2048

typedef short s16x8 __attribute__((ext_vector_type(8)));
typedef float f32x4 __attribute__((ext_vector_type(4)));

// swizzle: granule g (8 bf16) of row r stored at position (g + (r>>1)) & 3
#define TK_SWZ(g, r) (((g) + ((r) >> 1)) & 3)

#if __has_builtin(__builtin_amdgcn_global_load_lds)
#define GLOAD_LDS16(gp, lp) \
  __builtin_amdgcn_global_load_lds((const __attribute__((address_space(1))) unsigned int*)(gp), \
                                   (__attribute__((address_space(3))) unsigned int*)(lp), 16, 0, 0)
#define HAVE_GLLDS 1
#else
#define HAVE_GLLDS 0
#endif

// fast transcendentals: v_exp_f32 + v_rcp_f32
__device__ __forceinline__ float fsig_(float x){
  return __builtin_amdgcn_rcpf(1.f + __expf(-x));
}
__device__ __forceinline__ float ftanh_(float x){
  float e = __expf(2.f*x);
  return 1.f - 2.f*__builtin_amdgcn_rcpf(e + 1.f);
}
__device__ __forceinline__ unsigned short f2bf_(float f){
  unsigned int x = __float_as_uint(f);
  unsigned int r = (x + 0x7fffu + ((x>>16)&1u)) >> 16;
  return (unsigned short)r;
}
__device__ __forceinline__ float bfx_(unsigned int u){ return __uint_as_float(u << 16); }
// pack 2 floats to 2 bf16 (round-half-up) in one u32: low=a, high=b
__device__ __forceinline__ unsigned int pack_bf16_rnd(float a, float b){
  unsigned int ua = __float_as_uint(a) + 0x8000u;
  unsigned int ub = __float_as_uint(b) + 0x8000u;
  return __builtin_amdgcn_perm(ub, ua, 0x07060302u);
}
// row in the (2048 x 512) embedding buffer for (side, b, tok)
__device__ __forceinline__ int tokrow(int side, int b, int tok){
  return (((side*2 + (tok>>5))*16 + b) << 5) + (tok & 31);
}
// extract bf16 element idx from a uint4[3] register block (compile-time idx)
__device__ __forceinline__ float xiget_(const uint4* x4, int idx){
  const unsigned int* w = (const unsigned int*)x4;
  unsigned int v = w[idx >> 1];
  return (idx & 1) ? __uint_as_float(v & 0xffff0000u) : __uint_as_float(v << 16);
}

// ---------------- gather 4 fields into X0 (2048 x 768) ----------------
__global__ void k_gather(const float* __restrict__ f0, const float* __restrict__ f1,
                         const float* __restrict__ f2, const float* __restrict__ f3,
                         float* __restrict__ X0){
  int m = blockIdx.x;
  int f = m >> 9, rem = m & 511;
  const float* src = (f==0)? f0 : (f==1)? f1 : (f==2)? f2 : f3;
  const float* sp = src + (size_t)rem*NE;
  float* dp = X0 + (size_t)m*NE;
  for (int d = threadIdx.x; d < NE; d += 256) dp[d] = sp[d];
}

// ---------------- token & attribute masks ----------------
__global__ void k_masks(const float* __restrict__ f0, const float* __restrict__ f1,
                        const float* __restrict__ f2, const float* __restrict__ f3,
                        float* __restrict__ TM, float* __restrict__ AM){
  int f = blockIdx.x, b = blockIdx.y;
  const float* src = (f==0)? f0 : (f==1)? f1 : (f==2)? f2 : f3;
  __shared__ unsigned int flags[33];
  if (threadIdx.x < 33) flags[threadIdx.x] = 0u;
  __syncthreads();
  for (int t = 0; t < 32; t++){
    const float* row = src + ((size_t)b*NLF + t)*NE;
    bool nz = false;
    for (int d = threadIdx.x; d < NE; d += 256) nz |= (row[d] != 0.f);
    if (nz) atomicOr(&flags[t], 1u);
  }
  __syncthreads();
  int side = f >> 1, fi = f & 1;
  if (threadIdx.x < 32){
    unsigned int fl = flags[threadIdx.x];
    TM[side*1024 + b*64 + fi*32 + threadIdx.x] = fl ? 1.f : 0.f;
    if (fl) atomicOr(&flags[32], 1u);
  }
  __syncthreads();
  if (threadIdx.x == 0) AM[side*32 + b*2 + fi] = flags[32] ? 1.f : 0.f;
}

// ---------------- convert all 6 Whh chains to bf16 ----------------
__global__ void k_prep_whh(const float* __restrict__ w0, const float* __restrict__ w12,
                           unsigned short* __restrict__ dst){
  int idx = blockIdx.x*256 + threadIdx.x;   // < 1179648
  float v = (idx < 393216) ? w0[idx] : w12[idx - 393216];
  dst[idx] = f2bf_(v);
}

// ---------------- prep token weights: TW[nc][kc][n(interleaved)][k32] bf16, pre-swizzled ----------------
__global__ void k_prep_tw(const float* __restrict__ Wn, const float* __restrict__ Wg,
                          unsigned short* __restrict__ TW){
  int idx = blockIdx.x*256 + threadIdx.x;   // < 524288
  int kpos = idx & 31;
  int n    = (idx >> 5) & 127;
  int kc   = (idx >> 12) & 15;
  int nc   = idx >> 16;
  int gpos = kpos >> 3, j = kpos & 7;
  int gorig = (gpos - (n>>1)) & 3;
  int k = kc*32 + gorig*8 + j;
  int q = n >> 1, type = n & 1;
  const float* src = type ? Wg : Wn;
  TW[idx] = f2bf_(src[(size_t)(nc*64 + q)*NH2 + k]);
}

// ---------------- bf16 MFMA NT GEMM -> XI[dir][t][g][tid][24] bf16 (scan-thread order) ----------------
template<bool ABF16>
__global__ __launch_bounds__(256) void k_gemm_mfma(
    const void* __restrict__ Av,
    const float* __restrict__ Wb, long wsz,
    const float* __restrict__ biasb, long bsz,
    unsigned short* __restrict__ XIo, long csz,
    int K)
{
  int z = blockIdx.z;
  const float* W = Wb + (size_t)z*wsz;
  const float* bias = biasb + (size_t)z*bsz;
  unsigned short* XO = XIo + (size_t)z*csz;
  int n0 = blockIdx.x*128, m0 = blockIdx.y*128;
  __shared__ short At[128*32];
  __shared__ short Wt[128*32];
  int tid = threadIdx.x;
  int wave = tid >> 6, wm = wave >> 1, wn = wave & 1;
  int lane = tid & 63, l15 = lane & 15, lq = lane >> 4;
  int sm = tid & 127, gb = (tid >> 7) * 2;

  f32x4 zero4 = {0.f,0.f,0.f,0.f};
  f32x4 acc[4][4];
  #pragma unroll
  for (int mi=0;mi<4;mi++)
    #pragma unroll
    for (int nj=0;nj<4;nj++) acc[mi][nj] = zero4;

  const float* wr = W + (size_t)(n0 + sm)*K;

  for (int k0 = 0; k0 < K; k0 += 32){
    if constexpr (ABF16){
      const unsigned short* ar = (const unsigned short*)Av + (size_t)(m0 + sm)*K;
      #pragma unroll
      for (int gi = 0; gi < 2; gi++){
        int g = gb + gi;
        *(uint4*)&At[sm*32 + TK_SWZ(g,sm)*8] = *(const uint4*)&ar[k0 + g*8];
      }
    } else {
      const float* ar = (const float*)Av + (size_t)(m0 + sm)*K;
      #pragma unroll
      for (int gi = 0; gi < 2; gi++){
        int g = gb + gi;
        const float* ap = ar + k0 + g*8;
        float4 a0 = *(const float4*)ap, a1 = *(const float4*)(ap+4);
        uint4 pa = { pack_bf16_rnd(a0.x,a0.y), pack_bf16_rnd(a0.z,a0.w),
                     pack_bf16_rnd(a1.x,a1.y), pack_bf16_rnd(a1.z,a1.w) };
        *(uint4*)&At[sm*32 + TK_SWZ(g,sm)*8] = pa;
      }
    }
    #pragma unroll
    for (int gi = 0; gi < 2; gi++){
      int g = gb + gi;
      const float* wp = wr + k0 + g*8;
      float4 w0 = *(const float4*)wp, w1 = *(const float4*)(wp+4);
      uint4 pw = { pack_bf16_rnd(w0.x,w0.y), pack_bf16_rnd(w0.z,w0.w),
                   pack_bf16_rnd(w1.x,w1.y), pack_bf16_rnd(w1.z,w1.w) };
      *(uint4*)&Wt[sm*32 + TK_SWZ(g,sm)*8] = pw;
    }
    __syncthreads();
    s16x8 af[4], wf[4];
    #pragma unroll
    for (int mi=0;mi<4;mi++){
      int row = wm*64 + mi*16 + l15;
      af[mi] = *(const s16x8*)&At[row*32 + TK_SWZ(lq,row)*8];
    }
    #pragma unroll
    for (int nj=0;nj<4;nj++){
      int row = wn*64 + nj*16 + l15;
      wf[nj] = *(const s16x8*)&Wt[row*32 + TK_SWZ(lq,row)*8];
    }
    #pragma unroll
    for (int mi=0;mi<4;mi++)
      #pragma unroll
      for (int nj=0;nj<4;nj++)
        acc[mi][nj] = __builtin_amdgcn_mfma_f32_16x16x32_bf16(af[mi], wf[nj], acc[mi][nj], 0,0,0);
    __syncthreads();
  }
  // epilogue: write into scan-thread layout XI[t][g][tid_s][24]
  #pragma unroll
  for (int nj=0;nj<4;nj++){
    int n = n0 + wn*64 + nj*16 + l15;
    float bv = bias[n];
    int gg = n >> 8;
    int u256 = n & 255;
    int p = u256 >> 7, w_s = (u256 >> 4) & 7, l15_s = u256 & 15;
    int cofs = (p*3 + gg)*4;
    #pragma unroll
    for (int mi=0;mi<4;mi++){
      int mbase = m0 + wm*64 + mi*16 + lq*4;
      int t0 = mbase & 31, bp = mbase >> 5;
      int g = bp >> 4, mloc = bp & 15;
      int lq_s = mloc >> 2, r4 = mloc & 3;
      int tid_s = w_s*64 + lq_s*16 + l15_s;
      size_t base = ((size_t)(t0*4 + g)*512 + tid_s)*24 + cofs + r4;
      #pragma unroll
      for (int r=0;r<4;r++)
        XO[base + (size_t)r*49152] = f2bf_(acc[mi][nj][r] + bv);
    }
  }
}

// ---------------- GRU scan via MFMA; weights register-resident; deferred wide Hout ----------------
__global__ __launch_bounds__(512, 2) void k_scan_mfma(
    const unsigned short* __restrict__ xi,   // [2][32][4][512][24] bf16 (scan-thread order)
    const unsigned short* __restrict__ whh,  // [6][768][256] bf16
    const float* __restrict__ bhhb, long bhh_stride,
    unsigned short* __restrict__ Hout,       // [2048][512] bf16
    int chain0)
{
  int g = blockIdx.x;        // b' in [16g, 16g+16)
  int dir = blockIdx.y;
  int tid = threadIdx.x;
  int w = tid >> 6;
  int lane = tid & 63, l15 = lane & 15, lq = lane >> 4;
  const unsigned short* W = whh + (size_t)(chain0 + dir)*NG3*NH;
  const float* bhh = bhhb + (size_t)dir*bhh_stride;
  const unsigned short* xid = xi + (size_t)dir*1572864;
  int b0 = g*16;
  int hm = tid >> 5, hc = tid & 31;     // deferred-Hout writer role

  __shared__ unsigned short hbuf[2*16*264];
  for (int i = tid; i < 2*16*264; i += 512) hbuf[i] = 0;

  // prefetch step 0 xi (3 x 16B contiguous per thread)
  uint4 xc4[3], xn4[3];
  {
    int t0 = dir ? 31 : 0;
    const uint4* p0 = (const uint4*)(xid + ((size_t)(t0*4 + g)*512 + tid)*24);
    xc4[0] = p0[0]; xc4[1] = p0[1]; xc4[2] = p0[2];
  }

  // resident weight fragments: tile T = w + 8*p6, col c = 16T + l15
  s16x8 warr[6][8];
  #pragma unroll
  for (int p6 = 0; p6 < 6; p6++){
    const unsigned short* wp = W + (size_t)(16*(w + 8*p6) + l15)*NH + lq*8;
    #pragma unroll
    for (int kt = 0; kt < 8; kt++)
      warr[p6][kt] = *(const s16x8*)(wp + kt*32);
  }
  float brv[2], bzv[2], bnv[2];
  #pragma unroll
  for (int p = 0; p < 2; p++){
    int u = p*128 + 16*w + l15;
    brv[p] = bhh[u]; bzv[p] = bhh[256+u]; bnv[p] = bhh[512+u];
  }
  float hreg[2][4] = {{0,0,0,0},{0,0,0,0}};
  __syncthreads();

  for (int s = 0; s < 32; s++){
    int t = dir ? (31 - s) : s;
    int cur = s & 1;
    const unsigned short* rbp = hbuf + cur*4224;
    unsigned short* wbp = hbuf + (cur^1)*4224;

    // prefetch next step's xi (overlaps with MFMA + epilogue)
    if (s < 31){
      int tn = dir ? (31 - (s+1)) : (s+1);
      const uint4* pn = (const uint4*)(xid + ((size_t)(tn*4 + g)*512 + tid)*24);
      xn4[0] = pn[0]; xn4[1] = pn[1]; xn4[2] = pn[2];
    }
    // deferred wide Hout store of h(s-1), read cooperatively from rbp (stable this step)
    if (s > 0){
      int tp = dir ? (31 - (s-1)) : (s-1);
      uint4 hv = *(const uint4*)&rbp[hm*264 + hc*8];
      *(uint4*)&Hout[((size_t)(b0 + hm)*32 + tp)*NH2 + dir*256 + hc*8] = hv;
    }

    f32x4 acc[6];
    #pragma unroll
    for (int p6 = 0; p6 < 6; p6++) acc[p6] = (f32x4){0.f,0.f,0.f,0.f};
    #pragma unroll
    for (int kt = 0; kt < 8; kt++){
      s16x8 a = *(const s16x8*)&rbp[l15*264 + kt*32 + lq*8];
      #pragma unroll
      for (int p6 = 0; p6 < 6; p6++)
        acc[p6] = __builtin_amdgcn_mfma_f32_16x16x32_bf16(a, warr[p6][kt], acc[p6], 0,0,0);
    }

    #pragma unroll
    for (int p = 0; p < 2; p++){
      int u = p*128 + 16*w + l15;
      #pragma unroll
      for (int r4 = 0; r4 < 4; r4++){
        int m = lq*4 + r4;
        float xr_ = xiget_(xc4, (p*3+0)*4 + r4);
        float xz_ = xiget_(xc4, (p*3+1)*4 + r4);
        float xn_ = xiget_(xc4, (p*3+2)*4 + r4);
        float rr = fsig_(xr_ + acc[p][r4]   + brv[p]);
        float zz = fsig_(xz_ + acc[2+p][r4] + bzv[p]);
        float nn = ftanh_(xn_ + rr*(acc[4+p][r4] + bnv[p]));
        float hnew = (1.f - zz)*nn + zz*hreg[p][r4];
        hreg[p][r4] = hnew;
        wbp[m*264 + u] = f2bf_(hnew);
      }
    }
    if (s < 31){
      xc4[0] = xn4[0]; xc4[1] = xn4[1]; xc4[2] = xn4[2];
    }
    __syncthreads();
  }
  // tail: h(31) lives in hbuf[0] (step 31 wrote cur^1 = 0)
  {
    int tp = dir ? 0 : 31;
    uint4 hv = *(const uint4*)&hbuf[hm*264 + hc*8];
    *(uint4*)&Hout[((size_t)(b0 + hm)*32 + tp)*NH2 + dir*256 + hc*8] = hv;
  }
}

// ---------------- precompute cm tiles from bf16 H ----------------
__global__ __launch_bounds__(256) void k_cm_pretile(
    const unsigned short* __restrict__ Hf, unsigned short* __restrict__ CMT, int b0)
{
  int ip = blockIdx.x, bl = blockIdx.y;
  int b = b0 + bl;
  int tid = threadIdx.x;
  int m = tid & 127, gb = (tid >> 7) * 2;
  int i_ = ip*2 + (m >> 6), j_ = m & 63;
  const unsigned short* Lrow = Hf + (size_t)tokrow(0, b, i_)*NH2;
  const unsigned short* Rrow = Hf + (size_t)tokrow(1, b, j_)*NH2;
  unsigned short* dst = CMT + ((size_t)(bl*32 + ip) * 16) * 4096;
  for (int kc = 0; kc < 16; kc++){
    int k0 = kc*32;
    #pragma unroll
    for (int gi = 0; gi < 2; gi++){
      int g = gb + gi;
      uint4 lu = *(const uint4*)&Lrow[k0 + g*8];
      uint4 ru = *(const uint4*)&Rrow[k0 + g*8];
      unsigned int lw[4] = {lu.x, lu.y, lu.z, lu.w};
      unsigned int rw[4] = {ru.x, ru.y, ru.z, ru.w};
      uint4 pk;
      unsigned int pr[4];
      #pragma unroll
      for (int q = 0; q < 4; q++){
        float la = __uint_as_float(lw[q] << 16), lb = __uint_as_float(lw[q] & 0xffff0000u);
        float ra = __uint_as_float(rw[q] << 16), rb = __uint_as_float(rw[q] & 0xffff0000u);
        pr[q] = pack_bf16_rnd(fabsf(la - ra), fabsf(lb - rb));
      }
      pk.x = pr[0]; pk.y = pr[1]; pk.z = pr[2]; pk.w = pr[3];
      *(uint4*)&dst[kc*4096 + m*32 + TK_SWZ(g,m)*8] = pk;
    }
  }
}

// ---------------- token-matching scores via MFMA (DMA-staged tiles) ----------------
__global__ __launch_bounds__(256) void k_token_mfma(
    const unsigned short* __restrict__ CMT,
    const unsigned short* __restrict__ TW,
    const float* __restrict__ bn, const float* __restrict__ bg,
    const float* __restrict__ lintW,
    float* __restrict__ P, int b0)
{
  __shared__ short Atile[4096];
  __shared__ short Btile[4096];
  __shared__ short Asave[8192];
  __shared__ float sred[256];
  int ip = blockIdx.x, bl = blockIdx.y, nc = blockIdx.z;
  int b = b0 + bl;
  int tid = threadIdx.x;
  int wave = tid >> 6, wm = wave >> 1, wn = wave & 1;
  int lane = tid & 63, l15 = lane & 15, lq = lane >> 4;

  const char* Ab = (const char*)(CMT + ((size_t)(bl*32 + ip) * 16) * 4096);
  const char* Bb = (const char*)(TW + ((size_t)(nc*16)) * 4096);

  f32x4 zero4 = {0.f,0.f,0.f,0.f};
  f32x4 acc[4][4];
  #pragma unroll
  for (int mi=0;mi<4;mi++)
    #pragma unroll
    for (int nj=0;nj<4;nj++) acc[mi][nj] = zero4;

  for (int kc = 0; kc < 16; kc++){
    const char* gA = Ab + (size_t)kc*8192;
    const char* gB = Bb + (size_t)kc*8192;
#if HAVE_GLLDS
    char* lA = (char*)Atile + wave*1024;
    char* lB = (char*)Btile + wave*1024;
    GLOAD_LDS16(gA + tid*16, lA);
    GLOAD_LDS16(gA + 4096 + tid*16, lA + 4096);
    GLOAD_LDS16(gB + tid*16, lB);
    GLOAD_LDS16(gB + 4096 + tid*16, lB + 4096);
    int cs = kc - 2*nc;
    if ((unsigned)cs < 2u){
      char* lS = (char*)Asave + cs*8192 + wave*1024;
      GLOAD_LDS16(gA + tid*16, lS);
      GLOAD_LDS16(gA + 4096 + tid*16, lS + 4096);
    }
#else
    {
      uint4 va0 = ((const uint4*)gA)[tid], va1 = ((const uint4*)gA)[256+tid];
      uint4 vb0 = ((const uint4*)gB)[tid], vb1 = ((const uint4*)gB)[256+tid];
      ((uint4*)Atile)[tid] = va0; ((uint4*)Atile)[256+tid] = va1;
      ((uint4*)Btile)[tid] = vb0; ((uint4*)Btile)[256+tid] = vb1;
      int cs = kc - 2*nc;
      if ((unsigned)cs < 2u){
        ((uint4*)Asave)[cs*512 + tid] = va0; ((uint4*)Asave)[cs*512 + 256+tid] = va1;
      }
    }
#endif
    __syncthreads();
    s16x8 af[4], bfv[4];
    #pragma unroll
    for (int mi=0;mi<4;mi++){
      int row = wm*64 + mi*16 + l15;
      af[mi] = *(const s16x8*)&Atile[row*32 + TK_SWZ(lq,row)*8];
    }
    #pragma unroll
    for (int nj=0;nj<4;nj++){
      int row = wn*64 + nj*16 + l15;
      bfv[nj] = *(const s16x8*)&Btile[row*32 + TK_SWZ(lq,row)*8];
    }
    #pragma unroll
    for (int mi=0;mi<4;mi++)
      #pragma unroll
      for (int nj=0;nj<4;nj++)
        acc[mi][nj] = __builtin_amdgcn_mfma_f32_16x16x32_bf16(af[mi], bfv[nj], acc[mi][nj], 0,0,0);
    __syncthreads();
  }

  float bnv[4], bgv[4], lwv[4]; int qv[4];
  #pragma unroll
  for (int nj=0;nj<4;nj++){
    int q = (wn*64 + nj*16 + l15) >> 1;
    qv[nj] = q;
    int nf = nc*64 + q;
    bnv[nj] = bn[nf]; bgv[nj] = bg[nf]; lwv[nj] = lintW[nf];
  }
  float lmask = (l15 & 1) ? 0.f : 1.f;
  float sc[4][4];
  #pragma unroll
  for (int mi=0;mi<4;mi++)
    #pragma unroll
    for (int r=0;r<4;r++) sc[mi][r] = 0.f;

  #pragma unroll
  for (int nj=0;nj<4;nj++){
    int q = qv[nj];
    int cs = q >> 5, kk = q & 31, gor = kk >> 3, el = kk & 7;
    #pragma unroll
    for (int mi=0;mi<4;mi++){
      int mbase = wm*64 + mi*16 + lq*4;
      #pragma unroll
      for (int r=0;r<4;r++){
        float v  = acc[mi][nj][r];
        float pv = __shfl_xor(v, 1);
        int mm = mbase + r;
        unsigned short cu = (unsigned short)Asave[cs*4096 + mm*32 + TK_SWZ(gor,mm)*8 + el];
        float cmf = __uint_as_float(((unsigned int)cu) << 16);
        float an = v + bnv[nj];
        float gg = fsig_(pv + bgv[nj]);
        float hw = fmaxf(an, 0.f)*gg + (1.f - gg)*cmf;
        sc[mi][r] += lmask * lwv[nj] * hw;
      }
    }
  }
  #pragma unroll
  for (int mi=0;mi<4;mi++)
    #pragma unroll
    for (int r=0;r<4;r++){
      float v = sc[mi][r];
      v += __shfl_xor(v, 1); v += __shfl_xor(v, 2);
      v += __shfl_xor(v, 4); v += __shfl_xor(v, 8);
      sc[mi][r] = v;
    }
  if (l15 == 0){
    #pragma unroll
    for (int mi=0;mi<4;mi++)
      #pragma unroll
      for (int r=0;r<4;r++)
        sred[(wm*64 + mi*16 + lq*4 + r)*2 + wn] = sc[mi][r];
  }
  __syncthreads();
  if (tid < 128){
    float v = sred[tid*2] + sred[tid*2+1];
    int isel = tid >> 6, j = tid & 63;
    P[(((size_t)nc*16 + b)*64 + (ip*2 + isel))*64 + j] = v;
  }
}

__global__ void k_score_reduce(const float* __restrict__ P, float* __restrict__ S){
  int idx = blockIdx.x*256 + threadIdx.x;  // 65536
  float v = 0.f;
  #pragma unroll
  for (int nc = 0; nc < 8; nc++) v += P[(size_t)nc*65536 + idx];
  S[idx] = v;
}

// ---------------- softmaxes over j (w_l) and over i (w_r) ----------------
__global__ void k_softmax_wl(const float* __restrict__ S, const float* __restrict__ TM,
                             float* __restrict__ WLo){
  int i = blockIdx.x, b = blockIdx.y, j = threadIdx.x;
  float mask = TM[1024 + b*64 + j];
  float v = S[((size_t)b*64 + i)*64 + j] + (mask != 0.f ? 0.f : -1e10f);
  float m = v;
  for (int o = 32; o; o >>= 1) m = fmaxf(m, __shfl_xor(m, o));
  float e = __expf(v - m), s = e;
  for (int o = 32; o; o >>= 1) s += __shfl_xor(s, o);
  WLo[((size_t)b*64 + i)*64 + j] = e / s;
}
__global__ void k_softmax_wr(const float* __restrict__ S, const float* __restrict__ TM,
                             float* __restrict__ WRo){
  int j = blockIdx.x, b = blockIdx.y, i = threadIdx.x;
  float mask = TM[b*64 + i];
  float v = S[((size_t)b*64 + i)*64 + j] + (mask != 0.f ? 0.f : -1e10f);
  float m = v;
  for (int o = 32; o; o >>= 1) m = fmaxf(m, __shfl_xor(m, o));
  float e = __expf(v - m), s = e;
  for (int o = 32; o; o >>= 1) s += __shfl_xor(s, o);
  WRo[((size_t)b*64 + j)*64 + i] = e / s;
}

// ---------------- weighted |L-R| sums (bf16 H) ----------------
__global__ __launch_bounds__(256) void k_cmp(const unsigned short* __restrict__ Hf,
    const float* __restrict__ w, float* __restrict__ out, int side){
  int p = blockIdx.x, b = blockIdx.y;
  __shared__ float wl[64];
  if (threadIdx.x < 64) wl[threadIdx.x] = w[((size_t)b*64 + p)*64 + threadIdx.x];
  __syncthreads();
  int xr = tokrow(side, b, p);
  int d1 = threadIdx.x, d2 = threadIdx.x + 256;
  float x1 = bfx_(Hf[(size_t)xr*NH2 + d1]), x2 = bfx_(Hf[(size_t)xr*NH2 + d2]);
  float a1 = 0.f, a2 = 0.f;
  for (int q = 0; q < 64; q++){
    const unsigned short* yr = Hf + (size_t)tokrow(side^1, b, q)*NH2;
    float wq = wl[q];
    a1 += wq * fabsf(x1 - bfx_(yr[d1]));
    a2 += wq * fabsf(x2 - bfx_(yr[d2]));
  }
  out[((size_t)b*64 + p)*NH2 + d1] = a1;
  out[((size_t)b*64 + p)*NH2 + d2] = a2;
}

// ---------------- attribute matching -> concat buffer ----------------
__global__ __launch_bounds__(256) void k_attr(const unsigned short* __restrict__ Hf,
    const float* __restrict__ attrL, const float* __restrict__ attrR,
    const float* __restrict__ LC, const float* __restrict__ RC,
    const float* __restrict__ TM, const float* __restrict__ AM,
    const float* __restrict__ emptyA, float* __restrict__ CC){
  int fi = blockIdx.x, b = blockIdx.y, side = blockIdx.z;
  const float* attr = (side ? attrR : attrL) + fi*512;
  const float* cmp = side ? RC : LC;
  __shared__ float sc[32], wv[32];
  int t = threadIdx.x >> 3, l8 = threadIdx.x & 7;
  const unsigned short* er = Hf + (size_t)tokrow(side, b, fi*32 + t)*NH2;
  float acc = 0.f;
  for (int d = l8*64; d < l8*64 + 64; d++) acc += bfx_(er[d])*attr[d];
  acc += __shfl_down(acc, 4, 8);
  acc += __shfl_down(acc, 2, 8);
  acc += __shfl_down(acc, 1, 8);
  if (l8 == 0) sc[t] = acc;
  __syncthreads();
  if (threadIdx.x < 32){
    float mask = TM[side*1024 + b*64 + fi*32 + threadIdx.x];
    float v = sc[threadIdx.x] + (mask != 0.f ? 0.f : -1e10f);
    float m = v;
    for (int o = 16; o; o >>= 1) m = fmaxf(m, __shfl_xor(m, o, 32));
    float e = __expf(v - m), s = e;
    for (int o = 16; o; o >>= 1) s += __shfl_xor(s, o, 32);
    wv[threadIdx.x] = e / s;
  }
  __syncthreads();
  float am = AM[side*32 + b*2 + fi];
  int d1 = threadIdx.x, d2 = threadIdx.x + 256;
  float a1 = 0.f, a2 = 0.f;
  for (int t2 = 0; t2 < 32; t2++){
    float wq = wv[t2];
    const float* cr = cmp + ((size_t)b*64 + fi*32 + t2)*NH2;
    a1 += wq * cr[d1];
    a2 += wq * cr[d2];
  }
  float* dst = CC + (size_t)b*NDE + (size_t)(side*2 + fi)*512;
  dst[d1] = (am != 0.f) ? a1 : emptyA[d1];
  dst[d2] = (am != 0.f) ? a2 : emptyA[d2];
}

// ---------------- final highway: K-split MFMA GEMM -> partials ----------------
__global__ __launch_bounds__(256) void k_final_gemm(
    const float* __restrict__ X,     // CC [16][2048]
    const float* __restrict__ Wn, const float* __restrict__ Wg,
    float* __restrict__ P2)          // [2][4][16][2048]
{
  int nt = blockIdx.x, ks = blockIdx.y, z = blockIdx.z;
  const float* W = z ? Wg : Wn;
  int n0 = nt*64, k0 = ks*512;
  __shared__ short At[16*32];
  __shared__ short Wt[64*32];
  int tid = threadIdx.x;
  int w = tid >> 6, lane = tid & 63, l15 = lane & 15, lq = lane >> 4;
  int sm = tid & 63, gW = tid >> 6;
  int sa = tid & 15, ga = (tid >> 4) & 3;

  f32x4 acc = {0.f,0.f,0.f,0.f};
  for (int kc = 0; kc < 16; kc++){
    int kk = k0 + kc*32;
    {
      const float* wp = W + (size_t)(n0 + sm)*NDE + kk + gW*8;
      float4 w0 = *(const float4*)wp, w1 = *(const float4*)(wp+4);
      uint4 pw = { pack_bf16_rnd(w0.x,w0.y), pack_bf16_rnd(w0.z,w0.w),
                   pack_bf16_rnd(w1.x,w1.y), pack_bf16_rnd(w1.z,w1.w) };
      *(uint4*)&Wt[sm*32 + TK_SWZ(gW,sm)*8] = pw;
    }
    if (tid < 64){
      const float* xp = X + (size_t)sa*NDE + kk + ga*8;
      float4 x0 = *(const float4*)xp, x1 = *(const float4*)(xp+4);
      uint4 pa = { pack_bf16_rnd(x0.x,x0.y), pack_bf16_rnd(x0.z,x0.w),
                   pack_bf16_rnd(x1.x,x1.y), pack_bf16_rnd(x1.z,x1.w) };
      *(uint4*)&At[sa*32 + TK_SWZ(ga,sa)*8] = pa;
    }
    __syncthreads();
    s16x8 af = *(const s16x8*)&At[l15*32 + TK_SWZ(lq,l15)*8];
    int row = w*16 + l15;
    s16x8 bf = *(const s16x8*)&Wt[row*32 + TK_SWZ(lq,row)*8];
    acc = __builtin_amdgcn_mfma_f32_16x16x32_bf16(af, bf, acc, 0,0,0);
    __syncthreads();
  }
  int n = n0 + w*16 + l15;
  #pragma unroll
  for (int r = 0; r < 4; r++){
    int b = lq*4 + r;
    P2[(((size_t)z*4 + ks)*16 + b)*NDE + n] = acc[r];
  }
}

__global__ void k_final_reduce(const float* __restrict__ P2,
    const float* __restrict__ X, const float* __restrict__ bn, const float* __restrict__ bg,
    float* __restrict__ HWo){
  int idx = blockIdx.x*256 + threadIdx.x;   // 32768
  int b = idx >> 11, n = idx & 2047;
  float an = bn[n], ag = bg[n];
  #pragma unroll
  for (int ks = 0; ks < 4; ks++){
    an += P2[((size_t)(0*4 + ks)*16 + b)*NDE + n];
    ag += P2[((size_t)(1*4 + ks)*16 + b)*NDE + n];
  }
  float g = fsig_(ag);
  float x = X[(size_t)b*NDE + n];
  HWo[(size_t)b*NDE + n] = fmaxf(an, 0.f)*g + (1.f - g)*x;
}

// ---------------- linear + log_softmax ----------------
__global__ void k_out(const float* __restrict__ HWi, const float* __restrict__ lw,
                      const float* __restrict__ lb, float* __restrict__ out){
  int b = blockIdx.x, lane = threadIdx.x;
  float p0 = 0.f, p1 = 0.f;
  for (int n = lane; n < 2048; n += 64){
    float h = HWi[(size_t)b*NDE + n];
    p0 += h * lw[n];
    p1 += h * lw[2048 + n];
  }
  for (int o = 32; o; o >>= 1){ p0 += __shfl_xor(p0, o); p1 += __shfl_xor(p1, o); }
  if (lane == 0){
    float o0 = p0 + lb[0], o1 = p1 + lb[1];
    float m = fmaxf(o0, o1);
    float lse = m + logf(expf(o0 - m) + expf(o1 - m));
    out[b*2]   = o0 - lse;
    out[b*2+1] = o1 - lse;
  }
}

extern "C" void kernel_launch(void* const* d_in, const int* in_sizes, int n_in,
                              void* d_out, int out_size, void* d_ws, size_t ws_size,
                              hipStream_t stream){
  const float* lf0 = (const float*)d_in[0];
  const float* lf1 = (const float*)d_in[1];
  const float* rf0 = (const float*)d_in[2];
  const float* rf1 = (const float*)d_in[3];
  const float* gWih0 = (const float*)d_in[4];
  const float* gWhh0 = (const float*)d_in[5];
  const float* gbih0 = (const float*)d_in[6];
  const float* gbhh0 = (const float*)d_in[7];
  const float* gWih12 = (const float*)d_in[8];
  const float* gWhh12 = (const float*)d_in[9];
  const float* gbih12 = (const float*)d_in[10];
  const float* gbhh12 = (const float*)d_in[11];
  const float* hwtWn = (const float*)d_in[12];
  const float* hwtbn = (const float*)d_in[13];
  const float* hwtWg = (const float*)d_in[14];
  const float* hwtbg = (const float*)d_in[15];
  const float* lintW = (const float*)d_in[16];
  // d_in[17] = lintB (dropped: softmax is shift-invariant)
  const float* attrL = (const float*)d_in[18];
  const float* attrR = (const float*)d_in[19];
  const float* emptyA = (const float*)d_in[20];
  const float* hweWn = (const float*)d_in[21];
  const float* hwebn = (const float*)d_in[22];
  const float* hweWg = (const float*)d_in[23];
  const float* hwebg = (const float*)d_in[24];
  const float* lineW = (const float*)d_in[25];
  const float* lineB = (const float*)d_in[26];
  float* out = (float*)d_out;

  // ws layout (~29 MB): persistent first; CMT region (16 MB) aliases X0+XI and P2
  unsigned short* HA = (unsigned short*)d_ws;              // 1048576 sh (2 MB)
  unsigned short* HB = HA + 1048576;                       // 1048576 sh
  unsigned short* WHH = HB + 1048576;                      // 1179648 sh
  unsigned short* TW  = WHH + 1179648;                     // 524288 sh
  float* Sb  = (float*)(TW + 524288);                      // 65536
  float* WLb = Sb  + 65536;
  float* WRb = WLb + 65536;
  float* LC  = WRb + 65536;                                // 524288
  float* RC  = LC + 524288;                                // 524288
  float* TM  = RC + 524288;                                // 2048
  float* AM  = TM + 2048;                                  // 64
  float* CC  = AM + 64;                                    // 32768
  float* HWb = CC + 32768;                                 // 32768
  float* P   = HWb + 32768;                                // 524288
  unsigned short* CMT = (unsigned short*)(P + 524288);     // 8388608 sh (16 MB)
  float* X0 = (float*)CMT;                                 // aliases CMT (dead after gemms)
  unsigned short* XI = (unsigned short*)(X0 + 1572864);    // aliases CMT
  float* P2 = (float*)CMT;                                 // 262144 f (1 MB), after token loop

  k_gather<<<NBT, 256, 0, stream>>>(lf0, lf1, rf0, rf1, X0);
  k_masks<<<dim3(4,16), 256, 0, stream>>>(lf0, lf1, rf0, rf1, TM, AM);
  k_prep_whh<<<4608, 256, 0, stream>>>(gWhh0, gWhh12, WHH);
  k_prep_tw<<<2048, 256, 0, stream>>>(hwtWn, hwtWg, TW);

  const long XSZ = 1572864;   // per-dir XI shorts
  // layer 0 (A fp32)
  k_gemm_mfma<false><<<dim3(6,16,2), 256, 0, stream>>>(X0, gWih0, (long)NG3*NE, gbih0, NG3,
                                                       XI, XSZ, NE);
  k_scan_mfma<<<dim3(4,2), 512, 0, stream>>>(XI, WHH, gbhh0, NG3, HA, 0);
  // layer 1 (A bf16)
  k_gemm_mfma<true><<<dim3(6,16,2), 256, 0, stream>>>(HA, gWih12, (long)NG3*NH2, gbih12, NG3,
                                                      XI, XSZ, NH2);
  k_scan_mfma<<<dim3(4,2), 512, 0, stream>>>(XI, WHH, gbhh12, NG3, HB, 2);
  // layer 2 (A bf16)
  k_gemm_mfma<true><<<dim3(6,16,2), 256, 0, stream>>>(HB, gWih12 + (size_t)2*NG3*NH2, (long)NG3*NH2,
                                                      gbih12 + 2*NG3, NG3,
                                                      XI, XSZ, NH2);
  k_scan_mfma<<<dim3(4,2), 512, 0, stream>>>(XI, WHH, gbhh12 + 2*NG3, NG3, HA, 4);

  // token matching: 4 b-chunks of 4 (CMT reused per chunk; XI dead by now)
  for (int c = 0; c < 4; c++){
    k_cm_pretile<<<dim3(32,4), 256, 0, stream>>>(HA, CMT, c*4);
    k_token_mfma<<<dim3(32,4,8), 256, 0, stream>>>(CMT, TW, hwtbn, hwtbg, lintW, P, c*4);
  }
  k_score_reduce<<<256, 256, 0, stream>>>(P, Sb);
  k_softmax_wl<<<dim3(64,16), 64, 0, stream>>>(Sb, TM, WLb);
  k_softmax_wr<<<dim3(64,16), 64, 0, stream>>>(Sb, TM, WRb);
  k_cmp<<<dim3(64,16), 256, 0, stream>>>(HA, WLb, LC, 0);
  k_cmp<<<dim3(64,16), 256, 0, stream>>>(HA, WRb, RC, 1);

  // attribute matching -> concat
  k_attr<<<dim3(2,16,2), 256, 0, stream>>>(HA, attrL, attrR, LC, RC, TM, AM, emptyA, CC);

  // final highway (K-split MFMA) + classifier
  k_final_gemm<<<dim3(32,4,2), 256, 0, stream>>>(CC, hweWn, hweWg, P2);
  k_final_reduce<<<128, 256, 0, stream>>>(P2, CC, hwebn, hwebg, HWb);
  k_out<<<16, 64, 0, stream>>>(HWb, lineW, lineB, out);
}